// Round 3
// baseline (53.434 us; speedup 1.0000x reference)
//
#include <hip/hip_runtime.h>

// YOLOLayer: B=16, NA=3, NC=80, G=64, stride=8
// in : x[B][NA*85][64][64] f32   (channel-major)
// out: boxes[B*NA*4096][4] ++ conf[B*NA*4096] ++ cls[B*NA*4096][80]  (flat f32)
//
// Register-only streaming: no LDS, no barrier. Each lane owns 4 consecutive
// spatial positions; loops over channel-quads; the 4x4 transpose happens in
// registers and the 16B cls stores write-merge in L2 (adjacent k fills
// adjacent 16B of the same lines).

#define NB 16
#define NA 3
#define NC 80
#define GG 4096   // 64*64
#define CH 85     // 5 + NC

__device__ __forceinline__ float sigmoidf(float v) {
    return 1.0f / (1.0f + __expf(-v));
}

__global__ __launch_bounds__(128) void yolo_kernel(const float* __restrict__ x,
                                                   float* __restrict__ out) {
    const int blk  = blockIdx.x;          // 768 blocks
    const int tile = blk & 15;            // 16 tiles of 256 positions
    const int ba   = blk >> 4;            // b*NA + a, 0..47
    const int a    = ba % NA;
    const int lane = threadIdx.x & 63;
    const int wv   = threadIdx.x >> 6;    // 2 waves: channel-split, no sync
    const int p0   = tile * 256 + lane * 4;

    const float* __restrict__ xin = x + (size_t)ba * CH * GG + p0;
    const int loc0 = ba * GG + p0;

    float4* __restrict__ boxes4 = reinterpret_cast<float4*>(out);
    float*  __restrict__ conf   = out + (size_t)NB * NA * GG * 4;
    float4* __restrict__ cls4   =
        reinterpret_cast<float4*>(out + (size_t)NB * NA * GG * 5);

    int k0, k1;
    if (wv == 0) {
        // ---- channels 0..4: boxes + conf (wave 0 only) ----
        const float anchor_w[NA] = {0.1f * 64 * 8, 0.3f * 64 * 8, 0.6f * 64 * 8};
        const float anchor_h[NA] = {0.13f * 64 * 8, 0.35f * 64 * 8, 0.55f * 64 * 8};
        float4 c0 = *reinterpret_cast<const float4*>(xin + 0 * GG);
        float4 c1 = *reinterpret_cast<const float4*>(xin + 1 * GG);
        float4 c2 = *reinterpret_cast<const float4*>(xin + 2 * GG);
        float4 c3 = *reinterpret_cast<const float4*>(xin + 3 * GG);
        float4 c4 = *reinterpret_cast<const float4*>(xin + 4 * GG);
        const float aw = anchor_w[a], ah = anchor_h[a];
        #pragma unroll
        for (int q = 0; q < 4; ++q) {
            int p = p0 + q;
            float gx = (float)(p & 63);   // grid_x along last dim
            float gy = (float)(p >> 6);   // grid_y along dim -2
            float4 bx;
            bx.x = (sigmoidf(reinterpret_cast<float*>(&c0)[q]) + gx) * 8.0f;
            bx.y = (sigmoidf(reinterpret_cast<float*>(&c1)[q]) + gy) * 8.0f;
            bx.z = __expf(reinterpret_cast<float*>(&c2)[q]) * aw;
            bx.w = __expf(reinterpret_cast<float*>(&c3)[q]) * ah;
            boxes4[loc0 + q] = bx;        // lane's 4 stores cover 64B contiguous
        }
        float4 cf;
        cf.x = sigmoidf(c4.x); cf.y = sigmoidf(c4.y);
        cf.z = sigmoidf(c4.z); cf.w = sigmoidf(c4.w);
        *reinterpret_cast<float4*>(conf + loc0) = cf;   // contiguous 16B
        k0 = 0;  k1 = 10;
    } else {
        k0 = 10; k1 = 20;
    }

    // ---- cls: channel-quads; 4x4 register transpose per lane ----
    #pragma unroll 2
    for (int k = k0; k < k1; ++k) {
        const float* chp = xin + (size_t)(5 + 4 * k) * GG;
        float4 d0 = *reinterpret_cast<const float4*>(chp + 0 * GG);
        float4 d1 = *reinterpret_cast<const float4*>(chp + 1 * GG);
        float4 d2 = *reinterpret_cast<const float4*>(chp + 2 * GG);
        float4 d3 = *reinterpret_cast<const float4*>(chp + 3 * GG);
        #pragma unroll
        for (int q = 0; q < 4; ++q) {
            float4 v;
            v.x = sigmoidf(reinterpret_cast<float*>(&d0)[q]);
            v.y = sigmoidf(reinterpret_cast<float*>(&d1)[q]);
            v.z = sigmoidf(reinterpret_cast<float*>(&d2)[q]);
            v.w = sigmoidf(reinterpret_cast<float*>(&d3)[q]);
            // (pos*80 + 4k) floats -> float4 index pos*20 + k
            cls4[(size_t)(loc0 + q) * 20 + k] = v;
        }
    }
}

extern "C" void kernel_launch(void* const* d_in, const int* in_sizes, int n_in,
                              void* d_out, int out_size, void* d_ws, size_t ws_size,
                              hipStream_t stream) {
    const float* x = (const float*)d_in[0];
    float* out = (float*)d_out;
    dim3 grid(NB * NA * (GG / 256));      // 768 blocks, 2 waves each
    yolo_kernel<<<grid, 128, 0, stream>>>(x, out);
}

// Round 4
// 25.833 us; speedup vs baseline: 2.0684x; 2.0684x over previous
//
#include <hip/hip_runtime.h>
#include <stdint.h>

// YOLOLayer: B=16, NA=3, NC=80, G=64, stride=8
// in : x[B][NA*85][64][64] f32   (channel-major)
// out: boxes[B*NA*4096][4] ++ conf[B*NA*4096] ++ cls[B*NA*4096][80]  (flat f32)
//
// r4: r2 LDS-transpose structure, but
//  - global_load_lds (16B) staging: linear LDS dest + PRE-SWIZZLED global
//    source (rule #21), so reads can use the XOR-swizzled index (conflict-free)
//    while stores stay lane-contiguous.
//  - S=64 / 256 threads -> 21.25 KB LDS -> 7 blocks/CU: load/store phases of
//    co-resident blocks interleave, hiding the per-block barrier drain.

#define NB 16
#define NA 3
#define NC 80
#define GG 4096   // 64*64
#define CH 85     // 5 + NC
#define S  64     // spatial positions per block
#define NG (CH * (S / 4))   // 1360 float4 granules per tile

__device__ __forceinline__ float sigmoidf(float v) {
    return 1.0f / (1.0f + __expf(-v));
}

// Swizzled LDS float-index for (channel, position). Row stride = 64 floats.
// Granule XOR with (ch>>2)&7 spreads the cls read pattern (20 lanes sharing
// one p, consecutive channel-quads) across all 8 bank groups.
__device__ __forceinline__ int lidx(int ch, int p) {
    int g = (p >> 2) ^ ((ch >> 2) & 7);
    return (ch << 6) + (g << 2) + (p & 3);
}

__global__ __launch_bounds__(256) void yolo_kernel(const float* __restrict__ x,
                                                   float* __restrict__ out) {
    __shared__ float lds[CH * S];         // 21.25 KB -> 7 blocks/CU

    const int blk  = blockIdx.x;          // 3072 blocks
    const int tile = blk & 63;            // 64 tiles of 64 positions
    const int ba   = blk >> 6;            // b*NA + a
    const int a    = ba % NA;
    const int s0   = tile * S;
    const int tid  = threadIdx.x;
    const int lane = tid & 63;
    const int wv   = tid >> 6;

    const float* __restrict__ xin = x + (size_t)ba * CH * GG + s0;

    // ---- async stage: 1360 granules; lane l of the instruction lands at
    //      (uniform base + l*16B), so we fetch the float4 whose swizzled home
    //      is that linear slot: source granule = p4 ^ ((ch>>2)&7). ----
    #pragma unroll
    for (int it = 0; it < 6; ++it) {
        int g0 = it * 256 + wv * 64;      // wave-uniform granule base
        int g  = g0 + lane;
        if (g < NG) {
            int ch  = g >> 4;             // S/4 == 16 granules per row
            int p4  = g & 15;
            int sp4 = p4 ^ ((ch >> 2) & 7);
            const float* gp = xin + (size_t)ch * GG + (sp4 << 2);
            float* lp = &lds[g0 << 2];    // uniform; HW adds lane*16B
            __builtin_amdgcn_global_load_lds(
                (const __attribute__((address_space(1))) void*)gp,
                (__attribute__((address_space(3))) void*)lp,
                16, 0, 0);
        }
    }
    __syncthreads();

    // anchors scaled by g(=64) and STRIDE(=8): exact *8 scaling matches ref.
    const float anchor_w[NA] = {0.1f * 64 * 8, 0.3f * 64 * 8, 0.6f * 64 * 8};
    const float anchor_h[NA] = {0.13f * 64 * 8, 0.35f * 64 * 8, 0.55f * 64 * 8};

    const int loc = ba * GG + s0;
    float* __restrict__ boxes = out;                              // [..][4]
    float* __restrict__ conf  = out + (size_t)NB * NA * GG * 4;   // 786432
    float* __restrict__ cls   = out + (size_t)NB * NA * GG * 5;   // 983040

    // ---- boxes + conf: one thread per position ----
    if (tid < S) {
        int p  = tid;
        int sp = s0 + p;
        float gx = (float)(sp & 63);      // grid_x along last dim
        float gy = (float)(sp >> 6);      // grid_y along dim -2
        float4 bx;
        bx.x = (sigmoidf(lds[lidx(0, p)]) + gx) * 8.0f;
        bx.y = (sigmoidf(lds[lidx(1, p)]) + gy) * 8.0f;
        bx.z = __expf(lds[lidx(2, p)]) * anchor_w[a];
        bx.w = __expf(lds[lidx(3, p)]) * anchor_h[a];
        reinterpret_cast<float4*>(boxes)[loc + p] = bx;           // 1KB/wave
        conf[loc + p] = sigmoidf(lds[lidx(4, p)]);                // 256B/wave
    }

    // ---- cls: 80x64 outputs, float4 stores contiguous across lanes ----
    float4* __restrict__ cls4 =
        reinterpret_cast<float4*>(cls) + (size_t)loc * 20;
    #pragma unroll
    for (int i = tid; i < (S * 20); i += 256) {                   // 5 iters
        int p  = i / 20;                  // position
        int c4 = i % 20;                  // class-quad
        int r  = 5 + (c4 << 2);
        float4 v;
        v.x = sigmoidf(lds[lidx(r + 0, p)]);
        v.y = sigmoidf(lds[lidx(r + 1, p)]);
        v.z = sigmoidf(lds[lidx(r + 2, p)]);
        v.w = sigmoidf(lds[lidx(r + 3, p)]);
        cls4[i] = v;                      // 1KB contiguous per wave
    }
}

extern "C" void kernel_launch(void* const* d_in, const int* in_sizes, int n_in,
                              void* d_out, int out_size, void* d_ws, size_t ws_size,
                              hipStream_t stream) {
    const float* x = (const float*)d_in[0];
    float* out = (float*)d_out;
    dim3 grid(NB * NA * (GG / S));        // 3072 blocks
    yolo_kernel<<<grid, 256, 0, stream>>>(x, out);
}

// Round 5
// 25.168 us; speedup vs baseline: 2.1231x; 1.0264x over previous
//
#include <hip/hip_runtime.h>

// YOLOLayer: B=16, NA=3, NC=80, G=64, stride=8
// in : x[B][NA*85][64][64] f32   (channel-major)
// out: boxes[B*NA*4096][4] ++ conf[B*NA*4096] ++ cls[B*NA*4096][80]  (flat f32)
//
// r5: persistent double-buffered pipeline (T3/T4 at streaming scale):
//  - 768 blocks x 4 tiles; stage(t+1) issued BEFORE compute(t)
//  - counted s_waitcnt vmcnt(6): next tile's loads stay in flight across the
//    barrier (raw s_barrier, NOT __syncthreads which drains vmcnt to 0)
//  - every wave issues exactly 6 global_load_lds per tile (340 granules/wave,
//    last issue lane-masked) so vmcnt(6) is uniform-correct per wave
//  - staging keeps the r4 pre-swizzled-source trick (rule #21): linear LDS
//    dest, XOR-swizzled global source; reads use lidx() conflict-spread.

#define NB 16
#define NA 3
#define NC 80
#define GG 4096   // 64*64
#define CH 85     // 5 + NC
#define S  64     // spatial positions per tile
#define NG (CH * (S / 4))   // 1360 float4 granules per tile
#define GPW (NG / 4)        // 340 granules per wave
#define NT 4                // tiles per block
#define GRID (NB * NA * (GG / S) / NT)  // 768

__device__ __forceinline__ float sigmoidf(float v) {
    return 1.0f / (1.0f + __expf(-v));
}

// Swizzled LDS float-index for (channel, position). Row stride = 64 floats.
__device__ __forceinline__ int lidx(int ch, int p) {
    int g = (p >> 2) ^ ((ch >> 2) & 7);
    return (ch << 6) + (g << 2) + (p & 3);
}

__global__ __launch_bounds__(256) void yolo_kernel(const float* __restrict__ x,
                                                   float* __restrict__ out) {
    __shared__ float lds[2][CH * S];      // 2 x 21.25 KB -> 3 blocks/CU

    const int tid  = threadIdx.x;
    const int lane = tid & 63;
    const int wv   = tid >> 6;

    float* __restrict__ boxes = out;                              // [..][4]
    float* __restrict__ conf  = out + (size_t)NB * NA * GG * 4;
    float* __restrict__ cls   = out + (size_t)NB * NA * GG * 5;

    // ---- stage one tile into buf: exactly 6 global_load_lds per wave ----
    auto stage = [&](int tg, int buf) {
        const float* __restrict__ xin =
            x + (size_t)(tg >> 6) * CH * GG + (tg & 63) * S;
        #pragma unroll
        for (int it = 0; it < 6; ++it) {
            int g0 = wv * GPW + it * 64;  // wave-uniform granule base
            if (it * 64 + lane < GPW) {   // it<5: all lanes; it=5: lanes 0..19
                int g   = g0 + lane;
                int ch  = g >> 4;         // 16 granules per channel row
                int p4  = g & 15;
                int sp4 = p4 ^ ((ch >> 2) & 7);   // pre-swizzled source
                const float* gp = xin + (size_t)ch * GG + (sp4 << 2);
                float* lp = &lds[buf][g0 << 2];   // uniform; HW adds lane*16B
                __builtin_amdgcn_global_load_lds(
                    (const __attribute__((address_space(1))) void*)gp,
                    (__attribute__((address_space(3))) void*)lp,
                    16, 0, 0);
            }
        }
    };

    auto compute = [&](int tg, int buf) {
        const float* __restrict__ L = lds[buf];
        const int ba  = tg >> 6;
        const int a   = ba % NA;
        const int s0  = (tg & 63) * S;
        const int loc = ba * GG + s0;

        const float anchor_w[NA] = {0.1f * 64 * 8, 0.3f * 64 * 8, 0.6f * 64 * 8};
        const float anchor_h[NA] = {0.13f * 64 * 8, 0.35f * 64 * 8, 0.55f * 64 * 8};

        // boxes + conf: wave 0 only; other waves fall through to cls (no sync)
        if (tid < S) {
            int p  = tid;
            int sp = s0 + p;
            float gx = (float)(sp & 63);
            float gy = (float)(sp >> 6);
            float4 bx;
            bx.x = (sigmoidf(L[lidx(0, p)]) + gx) * 8.0f;
            bx.y = (sigmoidf(L[lidx(1, p)]) + gy) * 8.0f;
            bx.z = __expf(L[lidx(2, p)]) * anchor_w[a];
            bx.w = __expf(L[lidx(3, p)]) * anchor_h[a];
            reinterpret_cast<float4*>(boxes)[loc + p] = bx;       // 1KB/wave
            conf[loc + p] = sigmoidf(L[lidx(4, p)]);
        }

        // cls: 80x64 outputs, float4 stores contiguous across lanes
        float4* __restrict__ cls4 =
            reinterpret_cast<float4*>(cls) + (size_t)loc * 20;
        #pragma unroll
        for (int i0 = 0; i0 < 5; ++i0) {
            int i  = i0 * 256 + tid;
            int p  = i / 20;              // magic-mul
            int c4 = i % 20;
            int r  = 5 + (c4 << 2);
            float4 v;
            v.x = sigmoidf(L[lidx(r + 0, p)]);
            v.y = sigmoidf(L[lidx(r + 1, p)]);
            v.z = sigmoidf(L[lidx(r + 2, p)]);
            v.w = sigmoidf(L[lidx(r + 3, p)]);
            cls4[i] = v;                  // 1KB contiguous per wave
        }
    };

    const int tg0 = blockIdx.x * NT;      // 4 consecutive tiles per block

    stage(tg0, 0);                        // prologue
    #pragma unroll
    for (int k = 0; k < NT; ++k) {
        if (k + 1 < NT) {
            stage(tg0 + k + 1, (k + 1) & 1);
            // wait tile k's 6 loads; leave tile k+1's 6 in flight
            asm volatile("s_waitcnt vmcnt(6)" ::: "memory");
        } else {
            asm volatile("s_waitcnt vmcnt(0)" ::: "memory");
        }
        __builtin_amdgcn_s_barrier();     // raw: no vmcnt(0) drain
        __builtin_amdgcn_sched_barrier(0);// rule #18: pin ds_reads after barrier
        compute(tg0 + k, k & 1);
        __builtin_amdgcn_s_barrier();     // protect buf (k+1)&1 before restage
    }
}

extern "C" void kernel_launch(void* const* d_in, const int* in_sizes, int n_in,
                              void* d_out, int out_size, void* d_ws, size_t ws_size,
                              hipStream_t stream) {
    const float* x = (const float*)d_in[0];
    float* out = (float*)d_out;
    yolo_kernel<<<dim3(GRID), 256, 0, stream>>>(x, out);
}